// Round 5
// baseline (326.750 us; speedup 1.0000x reference)
//
#include <hip/hip_runtime.h>
#include <stdint.h>

#define T_SEQ 2048
#define CDIM 1024
#define NHEAD 16
#define HS 64

typedef __bf16 bf16x8 __attribute__((ext_vector_type(8)));
typedef float f32x4 __attribute__((ext_vector_type(4)));
typedef unsigned uint32x2 __attribute__((ext_vector_type(2)));

__device__ __forceinline__ unsigned short f2bf(float f) {
  union { float f; unsigned u; } c; c.f = f;
  unsigned r = c.u + 0x7FFFu + ((c.u >> 16) & 1u);
  return (unsigned short)(r >> 16);
}

__device__ __forceinline__ void gload_lds16(const void* g, void* l) {
  __builtin_amdgcn_global_load_lds((__attribute__((address_space(1))) void*)(g),
                                   (__attribute__((address_space(3))) void*)(l),
                                   16, 0, 0);
}

// x fp32 [4096][1024] -> bf16 same layout. 4 elems/thread.
__global__ __launch_bounds__(256) void k_cvt_x(const float* __restrict__ x,
                                               unsigned short* __restrict__ xb) {
  int i = blockIdx.x * 256 + threadIdx.x;
  float4 f = reinterpret_cast<const float4*>(x)[i];
  ushort4 u;
  u.x = f2bf(f.x); u.y = f2bf(f.y); u.z = f2bf(f.z); u.w = f2bf(f.w);
  reinterpret_cast<ushort4*>(xb)[i] = u;
}

// W [K][N] fp32 -> Wt [N][K] bf16 (tiled transpose)
__global__ __launch_bounds__(256) void k_transpose(const float* __restrict__ W,
                                                   unsigned short* __restrict__ Wt,
                                                   int K, int N) {
  __shared__ float tile[32][33];
  int n0 = blockIdx.x * 32, k0 = blockIdx.y * 32;
  int c = threadIdx.x & 31, r0 = threadIdx.x >> 5;
#pragma unroll
  for (int r = r0; r < 32; r += 8) tile[r][c] = W[(size_t)(k0 + r) * N + n0 + c];
  __syncthreads();
#pragma unroll
  for (int r = r0; r < 32; r += 8) Wt[(size_t)(n0 + r) * K + k0 + c] = f2bf(tile[c][r]);
}

// C = A[M][KD] * Bt[N][KD]^T + bias. 128x128 tile, 4 waves, BK=32.
// MODE 0: qkv scatter epilogue (bf16, K pre-scaled by 1/sqrt(hs)*log2e).
// MODE 1: fp32 out.
template <int MODE, int KD>
__global__ __launch_bounds__(256) void k_gemm(const unsigned short* __restrict__ A,
                                              const unsigned short* __restrict__ Bt,
                                              const float* __restrict__ bias,
                                              float* __restrict__ outF,
                                              unsigned short* __restrict__ qb,
                                              unsigned short* __restrict__ kb,
                                              unsigned short* __restrict__ vb) {
  __shared__ __align__(16) unsigned short Al[128 * 32];
  __shared__ __align__(16) unsigned short Bl[128 * 32];
  const int tid = threadIdx.x;
  const int wave = tid >> 6, lane = tid & 63;
  const int m0 = blockIdx.x * 128, n0 = blockIdx.y * 128;
  const int wr = (wave >> 1) * 64, wc = (wave & 1) * 64;
  const int srow = tid >> 2, scol = (tid & 3) * 8;
  const int ka = (lane >> 4) * 8;
  f32x4 acc[4][4];
#pragma unroll
  for (int m = 0; m < 4; ++m)
#pragma unroll
    for (int n = 0; n < 4; ++n) acc[m][n] = f32x4{0.f, 0.f, 0.f, 0.f};

  for (int k0 = 0; k0 < KD; k0 += 32) {
#pragma unroll
    for (int r = 0; r < 2; ++r) {
      gload_lds16(A + (size_t)(m0 + r * 64 + srow) * KD + k0 + scol,
                  (char*)Al + r * 4096 + wave * 1024);
      gload_lds16(Bt + (size_t)(n0 + r * 64 + srow) * KD + k0 + scol,
                  (char*)Bl + r * 4096 + wave * 1024);
    }
    __syncthreads();
    bf16x8 af[4], bfr[4];
#pragma unroll
    for (int m = 0; m < 4; ++m)
      af[m] = *(const bf16x8*)&Al[(wr + m * 16 + (lane & 15)) * 32 + ka];
#pragma unroll
    for (int n = 0; n < 4; ++n)
      bfr[n] = *(const bf16x8*)&Bl[(wc + n * 16 + (lane & 15)) * 32 + ka];
#pragma unroll
    for (int m = 0; m < 4; ++m)
#pragma unroll
      for (int n = 0; n < 4; ++n)
        acc[m][n] = __builtin_amdgcn_mfma_f32_16x16x32_bf16(af[m], bfr[n], acc[m][n], 0, 0, 0);
    __syncthreads();
  }

#pragma unroll
  for (int m = 0; m < 4; ++m)
#pragma unroll
    for (int n = 0; n < 4; ++n)
#pragma unroll
      for (int j = 0; j < 4; ++j) {
        int row = m0 + wr + m * 16 + (lane >> 4) * 4 + j;
        int col = n0 + wc + n * 16 + (lane & 15);
        float v = acc[m][n][j] + bias[col];
        if (MODE == 1) {
          outF[(size_t)row * CDIM + col] = v;
        } else {
          int which = col >> 10;
          int h = (col >> 6) & 15;
          int d = col & 63;
          int b = row >> 11, t = row & (T_SEQ - 1);
          int bh = b * NHEAD + h;
          // Fold attention scale (1/sqrt(64) * log2e) into K.
          unsigned short bv = f2bf(which == 1 ? v * 0.18033688f : v);
          if (which == 0)      qb[((size_t)bh * T_SEQ + t) * HS + d] = bv;
          else if (which == 1) kb[((size_t)bh * T_SEQ + t) * HS + d] = bv;
          else                 vb[((size_t)bh * HS + d) * T_SEQ + t] = bv;
        }
      }
}

// Flash attention, ZERO LDS. 2 waves/block; each wave owns 16 q-rows of the
// block's 32-row q-group (both waves read the same K/V lines -> L1 absorbs the
// duplicate traffic). Swapped QK^T (mfma(K,Q)) makes softmax lane-local; the
// cvt_pk-packed P (lane=q-row l15, k=mp*16+lh*4+j) is EXACTLY the A-fragment
// of v_mfma_f32_16x16x16_bf16, so PV runs straight from registers (16 MFMAs of
// K=16 per 64-key tile) -- no P round-trip, no barriers at all.
// K pre-scaled by 1/sqrt(hs)*log2e in GEMM1 epilogue (log2-domain scores).
// q,k: [bh][t][64] bf16; v: [bh][64][t] bf16 (transposed); y: [4096][1024] bf16.
__global__ __launch_bounds__(128, 4) void k_attn(const unsigned short* __restrict__ qb,
                                                 const unsigned short* __restrict__ kb,
                                                 const unsigned short* __restrict__ vb,
                                                 unsigned short* __restrict__ yb) {
  // rid -> (xcd, bh, q-group). 8 XCDs x 4 bh x 64 groups. Heavy groups first.
  const int rid = blockIdx.x;
  const int xcd = rid & 7, i = rid >> 3;       // i in 0..255
  const int bh = xcd * 4 + (i & 3);
  const int g = 63 - (i >> 2);                 // 63 (heaviest) down to 0
  const int wave = threadIdx.x >> 6;
  const int lane = threadIdx.x & 63;
  const int l15 = lane & 15, lh = lane >> 4;
  const int q0w = g * 32 + wave * 16;          // this wave's 16 q-rows
  const unsigned short* qh = qb + (size_t)bh * T_SEQ * HS;
  const unsigned short* kh = kb + (size_t)bh * T_SEQ * HS;
  const unsigned short* vh = vb + (size_t)bh * HS * T_SEQ;

  bf16x8 qf[2];
#pragma unroll
  for (int kk = 0; kk < 2; ++kk)
    qf[kk] = *(const bf16x8*)&qh[(size_t)(q0w + l15) * HS + kk * 32 + lh * 8];

  f32x4 o[4];                    // PV layout: q = lh*4 + j, d = n*16 + l15
  float Mx = -INFINITY, Ls = 0.f;  // softmax layout: q = l15 (per lane)
#pragma unroll
  for (int n = 0; n < 4; ++n) o[n] = f32x4{0.f, 0.f, 0.f, 0.f};

  const int nkt = (q0w >> 6) + 1;

  bf16x8 kf[4][2];
  // prologue: K fragments of tile 0
#pragma unroll
  for (int n = 0; n < 4; ++n)
#pragma unroll
    for (int kk = 0; kk < 2; ++kk)
      kf[n][kk] = *(const bf16x8*)&kh[(size_t)(n * 16 + l15) * HS + kk * 32 + lh * 8];

  for (int kt = 0; kt < nkt; ++kt) {
    const int kvb = kt * 64;
    // V fragments for 16x16x16 PV: B-frag = V^T[d=n*16+l15][k=mp*16+lh*4+0..3]
    uint32x2 v4[4][4];
#pragma unroll
    for (int n = 0; n < 4; ++n)
#pragma unroll
      for (int mp = 0; mp < 4; ++mp)
        v4[n][mp] = *(const uint32x2*)&vh[(size_t)(n * 16 + l15) * T_SEQ + kvb + mp * 16 + lh * 4];

    // Swapped QK^T: s2[mp] = S^T block, q = l15, k = kvb + mp*16 + lh*4 + j
    f32x4 s2[4];
#pragma unroll
    for (int mp = 0; mp < 4; ++mp) {
      f32x4 z = f32x4{0.f, 0.f, 0.f, 0.f};
      z = __builtin_amdgcn_mfma_f32_16x16x32_bf16(kf[mp][0], qf[0], z, 0, 0, 0);
      z = __builtin_amdgcn_mfma_f32_16x16x32_bf16(kf[mp][1], qf[1], z, 0, 0, 0);
      s2[mp] = z;
    }

    // K fragments for NEXT tile: old kf dead after the MFMAs above.
    if (kt + 1 < nkt) {
      const int kvb2 = kvb + 64;
#pragma unroll
      for (int n = 0; n < 4; ++n)
#pragma unroll
        for (int kk = 0; kk < 2; ++kk)
          kf[n][kk] = *(const bf16x8*)&kh[(size_t)(kvb2 + n * 16 + l15) * HS + kk * 32 + lh * 8];
    }

    const bool diag = (kvb + 63 > q0w);
    const int qg = q0w + l15;
    if (diag) {
#pragma unroll
      for (int mp = 0; mp < 4; ++mp)
#pragma unroll
        for (int j = 0; j < 4; ++j)
          if (kvb + mp * 16 + lh * 4 + j > qg) s2[mp][j] = -3.0e38f;
    }
    // in-register row max (full ILP) + 2-shfl cross-quadrant reduce
    f32x4 t01, t23, t;
#pragma unroll
    for (int e = 0; e < 4; ++e) {
      t01[e] = fmaxf(s2[0][e], s2[1][e]);
      t23[e] = fmaxf(s2[2][e], s2[3][e]);
      t[e] = fmaxf(t01[e], t23[e]);
    }
    float mx = fmaxf(fmaxf(t[0], t[1]), fmaxf(t[2], t[3]));
    mx = fmaxf(mx, __shfl_xor(mx, 16));
    mx = fmaxf(mx, __shfl_xor(mx, 32));
    const float newM = fmaxf(Mx, mx);
    const float al = __builtin_exp2f(Mx - newM);
    Mx = newM;
    float rs = 0.f;
    uint32x2 w[4];
#pragma unroll
    for (int mp = 0; mp < 4; ++mp) {
      float p0 = __builtin_exp2f(s2[mp][0] - newM);
      float p1 = __builtin_exp2f(s2[mp][1] - newM);
      float p2 = __builtin_exp2f(s2[mp][2] - newM);
      float p3 = __builtin_exp2f(s2[mp][3] - newM);
      rs += (p0 + p1) + (p2 + p3);
      unsigned lo, hi;
      asm("v_cvt_pk_bf16_f32 %0, %1, %2" : "=v"(lo) : "v"(p0), "v"(p1));
      asm("v_cvt_pk_bf16_f32 %0, %1, %2" : "=v"(hi) : "v"(p2), "v"(p3));
      w[mp][0] = lo; w[mp][1] = hi;
    }
    rs += __shfl_xor(rs, 16);
    rs += __shfl_xor(rs, 32);
    Ls = Ls * al + rs;

    // broadcast alpha to PV layout (alpha replicated across lh -> segment pull ok)
#pragma unroll
    for (int j = 0; j < 4; ++j) {
      const float a = __shfl(al, lh * 4 + j, 16);
#pragma unroll
      for (int n = 0; n < 4; ++n) o[n][j] *= a;
    }

    // PV: o += P * V via 16x16x16 MFMA, P straight from cvt_pk registers.
#pragma unroll
    for (int n = 0; n < 4; ++n)
#pragma unroll
      for (int mp = 0; mp < 4; ++mp)
        asm("v_mfma_f32_16x16x16_bf16 %0, %1, %2, %0"
            : "+v"(o[n]) : "v"(w[mp]), "v"(v4[n][mp]));
  }

  // MFMA write -> VALU read hazard guard before the epilogue touches o.
  asm volatile("s_nop 7\n\ts_nop 7" ::: );

  const int b = bh >> 4, h = bh & 15;
  const float inv = 1.0f / Ls;
#pragma unroll
  for (int j = 0; j < 4; ++j) {
    const float invj = __shfl(inv, lh * 4 + j, 16);
    const int tg = b * T_SEQ + q0w + lh * 4 + j;
#pragma unroll
    for (int n = 0; n < 4; ++n)
      yb[(size_t)tg * CDIM + h * 64 + n * 16 + l15] = f2bf(o[n][j] * invj);
  }
}

extern "C" void kernel_launch(void* const* d_in, const int* in_sizes, int n_in,
                              void* d_out, int out_size, void* d_ws, size_t ws_size,
                              hipStream_t stream) {
  (void)in_sizes; (void)n_in; (void)out_size; (void)ws_size;
  const float* x      = (const float*)d_in[0];
  const float* W_attn = (const float*)d_in[1];
  const float* b_attn = (const float*)d_in[2];
  const float* W_proj = (const float*)d_in[3];
  const float* b_proj = (const float*)d_in[4];
  float* out = (float*)d_out;
  char* ws = (char*)d_ws;

  unsigned short* xb  = (unsigned short*)(ws);              //  8 MiB [4096][1024]
  unsigned short* Wta = (unsigned short*)(ws + 8388608);    //  6 MiB [3072][1024]
  unsigned short* Wtp = (unsigned short*)(ws + 14680064);   //  2 MiB [1024][1024]
  unsigned short* qbf = (unsigned short*)(ws + 16777216);   //  8 MiB [32][2048][64]
  unsigned short* kbf = (unsigned short*)(ws + 25165824);   //  8 MiB [32][2048][64]
  unsigned short* vbf = (unsigned short*)(ws + 33554432);   //  8 MiB [32][64][2048]
  unsigned short* ybf = (unsigned short*)(ws + 41943040);   //  8 MiB [4096][1024]

  k_cvt_x<<<4096, 256, 0, stream>>>(x, xb);
  k_transpose<<<dim3(96, 32), 256, 0, stream>>>(W_attn, Wta, 1024, 3072);
  k_transpose<<<dim3(32, 32), 256, 0, stream>>>(W_proj, Wtp, 1024, 1024);
  k_gemm<0, 1024><<<dim3(32, 24), 256, 0, stream>>>(xb, Wta, b_attn, nullptr, qbf, kbf, vbf);
  k_attn<<<2048, 128, 0, stream>>>(qbf, kbf, vbf, ybf);
  k_gemm<1, 1024><<<dim3(32, 8), 256, 0, stream>>>(ybf, Wtp, b_proj, out, nullptr, nullptr, nullptr);
}

// Round 7
// 255.983 us; speedup vs baseline: 1.2765x; 1.2765x over previous
//
#include <hip/hip_runtime.h>
#include <stdint.h>

#define T_SEQ 2048
#define CDIM 1024
#define NHEAD 16
#define HS 64

typedef __bf16 bf16x8 __attribute__((ext_vector_type(8)));
typedef float f32x4 __attribute__((ext_vector_type(4)));
typedef short s16x4 __attribute__((ext_vector_type(4)));

__device__ __forceinline__ unsigned short f2bf(float f) {
  union { float f; unsigned u; } c; c.f = f;
  unsigned r = c.u + 0x7FFFu + ((c.u >> 16) & 1u);
  return (unsigned short)(r >> 16);
}

__device__ __forceinline__ void gload_lds16(const void* g, void* l) {
  __builtin_amdgcn_global_load_lds((__attribute__((address_space(1))) void*)(g),
                                   (__attribute__((address_space(3))) void*)(l),
                                   16, 0, 0);
}

// x fp32 [4096][1024] -> bf16 same layout. 4 elems/thread.
__global__ __launch_bounds__(256) void k_cvt_x(const float* __restrict__ x,
                                               unsigned short* __restrict__ xb) {
  int i = blockIdx.x * 256 + threadIdx.x;
  float4 f = reinterpret_cast<const float4*>(x)[i];
  ushort4 u;
  u.x = f2bf(f.x); u.y = f2bf(f.y); u.z = f2bf(f.z); u.w = f2bf(f.w);
  reinterpret_cast<ushort4*>(xb)[i] = u;
}

// W [K][N] fp32 -> Wt [N][K] bf16 (tiled transpose)
__global__ __launch_bounds__(256) void k_transpose(const float* __restrict__ W,
                                                   unsigned short* __restrict__ Wt,
                                                   int K, int N) {
  __shared__ float tile[32][33];
  int n0 = blockIdx.x * 32, k0 = blockIdx.y * 32;
  int c = threadIdx.x & 31, r0 = threadIdx.x >> 5;
#pragma unroll
  for (int r = r0; r < 32; r += 8) tile[r][c] = W[(size_t)(k0 + r) * N + n0 + c];
  __syncthreads();
#pragma unroll
  for (int r = r0; r < 32; r += 8) Wt[(size_t)(n0 + r) * K + k0 + c] = f2bf(tile[c][r]);
}

// C = A[M][KD] * Bt[N][KD]^T + bias. 128x128 tile, 4 waves, BK=32.
// MODE 0: qkv scatter epilogue (bf16, K pre-scaled by 1/sqrt(hs)*log2e).
// MODE 1: fp32 out.
template <int MODE, int KD>
__global__ __launch_bounds__(256) void k_gemm(const unsigned short* __restrict__ A,
                                              const unsigned short* __restrict__ Bt,
                                              const float* __restrict__ bias,
                                              float* __restrict__ outF,
                                              unsigned short* __restrict__ qb,
                                              unsigned short* __restrict__ kb,
                                              unsigned short* __restrict__ vb) {
  __shared__ __align__(16) unsigned short Al[128 * 32];
  __shared__ __align__(16) unsigned short Bl[128 * 32];
  const int tid = threadIdx.x;
  const int wave = tid >> 6, lane = tid & 63;
  const int m0 = blockIdx.x * 128, n0 = blockIdx.y * 128;
  const int wr = (wave >> 1) * 64, wc = (wave & 1) * 64;
  const int srow = tid >> 2, scol = (tid & 3) * 8;
  const int ka = (lane >> 4) * 8;
  f32x4 acc[4][4];
#pragma unroll
  for (int m = 0; m < 4; ++m)
#pragma unroll
    for (int n = 0; n < 4; ++n) acc[m][n] = f32x4{0.f, 0.f, 0.f, 0.f};

  for (int k0 = 0; k0 < KD; k0 += 32) {
#pragma unroll
    for (int r = 0; r < 2; ++r) {
      gload_lds16(A + (size_t)(m0 + r * 64 + srow) * KD + k0 + scol,
                  (char*)Al + r * 4096 + wave * 1024);
      gload_lds16(Bt + (size_t)(n0 + r * 64 + srow) * KD + k0 + scol,
                  (char*)Bl + r * 4096 + wave * 1024);
    }
    __syncthreads();
    bf16x8 af[4], bfr[4];
#pragma unroll
    for (int m = 0; m < 4; ++m)
      af[m] = *(const bf16x8*)&Al[(wr + m * 16 + (lane & 15)) * 32 + ka];
#pragma unroll
    for (int n = 0; n < 4; ++n)
      bfr[n] = *(const bf16x8*)&Bl[(wc + n * 16 + (lane & 15)) * 32 + ka];
#pragma unroll
    for (int m = 0; m < 4; ++m)
#pragma unroll
      for (int n = 0; n < 4; ++n)
        acc[m][n] = __builtin_amdgcn_mfma_f32_16x16x32_bf16(af[m], bfr[n], acc[m][n], 0, 0, 0);
    __syncthreads();
  }

#pragma unroll
  for (int m = 0; m < 4; ++m)
#pragma unroll
    for (int n = 0; n < 4; ++n)
#pragma unroll
      for (int j = 0; j < 4; ++j) {
        int row = m0 + wr + m * 16 + (lane >> 4) * 4 + j;
        int col = n0 + wc + n * 16 + (lane & 15);
        float v = acc[m][n][j] + bias[col];
        if (MODE == 1) {
          outF[(size_t)row * CDIM + col] = v;
        } else {
          int which = col >> 10;
          int h = (col >> 6) & 15;
          int d = col & 63;
          int b = row >> 11, t = row & (T_SEQ - 1);
          int bh = b * NHEAD + h;
          // Fold attention scale (1/sqrt(64) * log2e) into K.
          unsigned short bv = f2bf(which == 1 ? v * 0.18033688f : v);
          if (which == 0)      qb[((size_t)bh * T_SEQ + t) * HS + d] = bv;
          else if (which == 1) kb[((size_t)bh * T_SEQ + t) * HS + d] = bv;
          else                 vb[((size_t)bh * HS + d) * T_SEQ + t] = bv;
        }
      }
}

// Flash attention, ZERO LDS. 2 waves/block; each wave owns 16 q-rows of the
// block's 32-row q-group (both waves read the same K/V lines -> L1 absorbs the
// duplicate traffic). Swapped QK^T (mfma(K,Q)) makes softmax lane-local; the
// cvt_pk-packed P (lane=q-row l15, k=mp*16+lh*4+j) is EXACTLY the A-fragment
// of v_mfma_f32_16x16x16_bf16, so PV runs straight from registers -- no P
// round-trip, no barriers. PV uses the BUILTIN mfma_f32_16x16x16bf16_1k:
// R5's inline-asm MFMA NaN'd because the compiler can't see MFMA hazards
// inside asm blobs and hoisted dependent VALU reads into the hazard window
// (R4's spill code had masked it). Builtin -> compiler-managed hazards.
// K pre-scaled by 1/sqrt(hs)*log2e in GEMM1 epilogue (log2-domain scores).
// q,k: [bh][t][64] bf16; v: [bh][64][t] bf16 (transposed); y: [4096][1024] bf16.
__global__ __launch_bounds__(128) void k_attn(const unsigned short* __restrict__ qb,
                                              const unsigned short* __restrict__ kb,
                                              const unsigned short* __restrict__ vb,
                                              unsigned short* __restrict__ yb) {
  // rid -> (xcd, bh, q-group). 8 XCDs x 4 bh x 64 groups. Heavy groups first.
  const int rid = blockIdx.x;
  const int xcd = rid & 7, i = rid >> 3;       // i in 0..255
  const int bh = xcd * 4 + (i & 3);
  const int g = 63 - (i >> 2);                 // 63 (heaviest) down to 0
  const int wave = threadIdx.x >> 6;
  const int lane = threadIdx.x & 63;
  const int l15 = lane & 15, lh = lane >> 4;
  const int q0w = g * 32 + wave * 16;          // this wave's 16 q-rows
  const unsigned short* qh = qb + (size_t)bh * T_SEQ * HS;
  const unsigned short* kh = kb + (size_t)bh * T_SEQ * HS;
  const unsigned short* vh = vb + (size_t)bh * HS * T_SEQ;

  bf16x8 qf[2];
#pragma unroll
  for (int kk = 0; kk < 2; ++kk)
    qf[kk] = *(const bf16x8*)&qh[(size_t)(q0w + l15) * HS + kk * 32 + lh * 8];

  f32x4 o[4];                    // PV layout: q = lh*4 + j, d = n*16 + l15
  float Mx = -INFINITY, Ls = 0.f;  // softmax layout: q = l15 (per lane)
#pragma unroll
  for (int n = 0; n < 4; ++n) o[n] = f32x4{0.f, 0.f, 0.f, 0.f};

  const int nkt = (q0w >> 6) + 1;

  bf16x8 kf[4][2];
  // prologue: K fragments of tile 0
#pragma unroll
  for (int n = 0; n < 4; ++n)
#pragma unroll
    for (int kk = 0; kk < 2; ++kk)
      kf[n][kk] = *(const bf16x8*)&kh[(size_t)(n * 16 + l15) * HS + kk * 32 + lh * 8];

  for (int kt = 0; kt < nkt; ++kt) {
    const int kvb = kt * 64;
    // V fragments for 16x16x16 PV: B-frag = V^T[d=n*16+l15][k=mp*16+lh*4+0..3]
    s16x4 v4[4][4];
#pragma unroll
    for (int n = 0; n < 4; ++n)
#pragma unroll
      for (int mp = 0; mp < 4; ++mp)
        v4[n][mp] = *(const s16x4*)&vh[(size_t)(n * 16 + l15) * T_SEQ + kvb + mp * 16 + lh * 4];

    // Swapped QK^T: s2[mp] = S^T block, q = l15, k = kvb + mp*16 + lh*4 + j
    f32x4 s2[4];
#pragma unroll
    for (int mp = 0; mp < 4; ++mp) {
      f32x4 z = f32x4{0.f, 0.f, 0.f, 0.f};
      z = __builtin_amdgcn_mfma_f32_16x16x32_bf16(kf[mp][0], qf[0], z, 0, 0, 0);
      z = __builtin_amdgcn_mfma_f32_16x16x32_bf16(kf[mp][1], qf[1], z, 0, 0, 0);
      s2[mp] = z;
    }

    // K fragments for NEXT tile: old kf dead after the MFMAs above.
    if (kt + 1 < nkt) {
      const int kvb2 = kvb + 64;
#pragma unroll
      for (int n = 0; n < 4; ++n)
#pragma unroll
        for (int kk = 0; kk < 2; ++kk)
          kf[n][kk] = *(const bf16x8*)&kh[(size_t)(kvb2 + n * 16 + l15) * HS + kk * 32 + lh * 8];
    }

    const bool diag = (kvb + 63 > q0w);
    const int qg = q0w + l15;
    if (diag) {
#pragma unroll
      for (int mp = 0; mp < 4; ++mp)
#pragma unroll
        for (int j = 0; j < 4; ++j)
          if (kvb + mp * 16 + lh * 4 + j > qg) s2[mp][j] = -3.0e38f;
    }
    // in-register row max (full ILP) + 2-shfl cross-quadrant reduce
    f32x4 t01, t23, t;
#pragma unroll
    for (int e = 0; e < 4; ++e) {
      t01[e] = fmaxf(s2[0][e], s2[1][e]);
      t23[e] = fmaxf(s2[2][e], s2[3][e]);
      t[e] = fmaxf(t01[e], t23[e]);
    }
    float mx = fmaxf(fmaxf(t[0], t[1]), fmaxf(t[2], t[3]));
    mx = fmaxf(mx, __shfl_xor(mx, 16));
    mx = fmaxf(mx, __shfl_xor(mx, 32));
    const float newM = fmaxf(Mx, mx);
    const float al = __builtin_exp2f(Mx - newM);
    Mx = newM;
    float rs = 0.f;
    s16x4 w4[4];
#pragma unroll
    for (int mp = 0; mp < 4; ++mp) {
      float p0 = __builtin_exp2f(s2[mp][0] - newM);
      float p1 = __builtin_exp2f(s2[mp][1] - newM);
      float p2 = __builtin_exp2f(s2[mp][2] - newM);
      float p3 = __builtin_exp2f(s2[mp][3] - newM);
      rs += (p0 + p1) + (p2 + p3);
      unsigned lo, hi;
      asm("v_cvt_pk_bf16_f32 %0, %1, %2" : "=v"(lo) : "v"(p0), "v"(p1));
      asm("v_cvt_pk_bf16_f32 %0, %1, %2" : "=v"(hi) : "v"(p2), "v"(p3));
      union { unsigned u[2]; s16x4 s; } cv;
      cv.u[0] = lo; cv.u[1] = hi;
      w4[mp] = cv.s;
    }
    rs += __shfl_xor(rs, 16);
    rs += __shfl_xor(rs, 32);
    Ls = Ls * al + rs;

    // broadcast alpha to PV layout (alpha replicated across lh -> segment pull ok)
#pragma unroll
    for (int j = 0; j < 4; ++j) {
      const float a = __shfl(al, lh * 4 + j, 16);
#pragma unroll
      for (int n = 0; n < 4; ++n) o[n][j] *= a;
    }

    // PV: o += P * V via builtin 16x16x16 MFMA, P straight from cvt_pk regs.
#pragma unroll
    for (int n = 0; n < 4; ++n)
#pragma unroll
      for (int mp = 0; mp < 4; ++mp)
        o[n] = __builtin_amdgcn_mfma_f32_16x16x16bf16_1k(w4[mp], v4[n][mp], o[n], 0, 0, 0);
  }

  const int b = bh >> 4, h = bh & 15;
  const float inv = 1.0f / Ls;
#pragma unroll
  for (int j = 0; j < 4; ++j) {
    const float invj = __shfl(inv, lh * 4 + j, 16);
    const int tg = b * T_SEQ + q0w + lh * 4 + j;
#pragma unroll
    for (int n = 0; n < 4; ++n)
      yb[(size_t)tg * CDIM + h * 64 + n * 16 + l15] = f2bf(o[n][j] * invj);
  }
}

extern "C" void kernel_launch(void* const* d_in, const int* in_sizes, int n_in,
                              void* d_out, int out_size, void* d_ws, size_t ws_size,
                              hipStream_t stream) {
  (void)in_sizes; (void)n_in; (void)out_size; (void)ws_size;
  const float* x      = (const float*)d_in[0];
  const float* W_attn = (const float*)d_in[1];
  const float* b_attn = (const float*)d_in[2];
  const float* W_proj = (const float*)d_in[3];
  const float* b_proj = (const float*)d_in[4];
  float* out = (float*)d_out;
  char* ws = (char*)d_ws;

  unsigned short* xb  = (unsigned short*)(ws);              //  8 MiB [4096][1024]
  unsigned short* Wta = (unsigned short*)(ws + 8388608);    //  6 MiB [3072][1024]
  unsigned short* Wtp = (unsigned short*)(ws + 14680064);   //  2 MiB [1024][1024]
  unsigned short* qbf = (unsigned short*)(ws + 16777216);   //  8 MiB [32][2048][64]
  unsigned short* kbf = (unsigned short*)(ws + 25165824);   //  8 MiB [32][2048][64]
  unsigned short* vbf = (unsigned short*)(ws + 33554432);   //  8 MiB [32][64][2048]
  unsigned short* ybf = (unsigned short*)(ws + 41943040);   //  8 MiB [4096][1024]

  k_cvt_x<<<4096, 256, 0, stream>>>(x, xb);
  k_transpose<<<dim3(96, 32), 256, 0, stream>>>(W_attn, Wta, 1024, 3072);
  k_transpose<<<dim3(32, 32), 256, 0, stream>>>(W_proj, Wtp, 1024, 1024);
  k_gemm<0, 1024><<<dim3(32, 24), 256, 0, stream>>>(xb, Wta, b_attn, nullptr, qbf, kbf, vbf);
  k_attn<<<2048, 128, 0, stream>>>(qbf, kbf, vbf, ybf);
  k_gemm<1, 1024><<<dim3(32, 8), 256, 0, stream>>>(ybf, Wtp, b_proj, out, nullptr, nullptr, nullptr);
}

// Round 8
// 150.717 us; speedup vs baseline: 2.1680x; 1.6984x over previous
//
#include <hip/hip_runtime.h>
#include <stdint.h>

#define T_SEQ 2048
#define CDIM 1024
#define NHEAD 16
#define HS 64

typedef __bf16 bf16x8 __attribute__((ext_vector_type(8)));
typedef float f32x4 __attribute__((ext_vector_type(4)));

__device__ __forceinline__ unsigned short f2bf(float f) {
  union { float f; unsigned u; } c; c.f = f;
  unsigned r = c.u + 0x7FFFu + ((c.u >> 16) & 1u);
  return (unsigned short)(r >> 16);
}

__device__ __forceinline__ void gload_lds16(const void* g, void* l) {
  __builtin_amdgcn_global_load_lds((__attribute__((address_space(1))) void*)(g),
                                   (__attribute__((address_space(3))) void*)(l),
                                   16, 0, 0);
}

// x fp32 [4096][1024] -> bf16 same layout. 4 elems/thread.
__global__ __launch_bounds__(256) void k_cvt_x(const float* __restrict__ x,
                                               unsigned short* __restrict__ xb) {
  int i = blockIdx.x * 256 + threadIdx.x;
  float4 f = reinterpret_cast<const float4*>(x)[i];
  ushort4 u;
  u.x = f2bf(f.x); u.y = f2bf(f.y); u.z = f2bf(f.z); u.w = f2bf(f.w);
  reinterpret_cast<ushort4*>(xb)[i] = u;
}

// W [K][N] fp32 -> Wt [N][K] bf16 (tiled transpose)
__global__ __launch_bounds__(256) void k_transpose(const float* __restrict__ W,
                                                   unsigned short* __restrict__ Wt,
                                                   int K, int N) {
  __shared__ float tile[32][33];
  int n0 = blockIdx.x * 32, k0 = blockIdx.y * 32;
  int c = threadIdx.x & 31, r0 = threadIdx.x >> 5;
#pragma unroll
  for (int r = r0; r < 32; r += 8) tile[r][c] = W[(size_t)(k0 + r) * N + n0 + c];
  __syncthreads();
#pragma unroll
  for (int r = r0; r < 32; r += 8) Wt[(size_t)(n0 + r) * K + k0 + c] = f2bf(tile[c][r]);
}

// C = A[M][KD] * Bt[N][KD]^T + bias. 128x128 tile, 4 waves, BK=32.
// MODE 0: qkv scatter epilogue (bf16, K pre-scaled by 1/sqrt(hs)*log2e).
// MODE 1: fp32 out.
template <int MODE, int KD>
__global__ __launch_bounds__(256) void k_gemm(const unsigned short* __restrict__ A,
                                              const unsigned short* __restrict__ Bt,
                                              const float* __restrict__ bias,
                                              float* __restrict__ outF,
                                              unsigned short* __restrict__ qb,
                                              unsigned short* __restrict__ kb,
                                              unsigned short* __restrict__ vb) {
  __shared__ __align__(16) unsigned short Al[128 * 32];
  __shared__ __align__(16) unsigned short Bl[128 * 32];
  const int tid = threadIdx.x;
  const int wave = tid >> 6, lane = tid & 63;
  const int m0 = blockIdx.x * 128, n0 = blockIdx.y * 128;
  const int wr = (wave >> 1) * 64, wc = (wave & 1) * 64;
  const int srow = tid >> 2, scol = (tid & 3) * 8;
  const int ka = (lane >> 4) * 8;
  f32x4 acc[4][4];
#pragma unroll
  for (int m = 0; m < 4; ++m)
#pragma unroll
    for (int n = 0; n < 4; ++n) acc[m][n] = f32x4{0.f, 0.f, 0.f, 0.f};

  for (int k0 = 0; k0 < KD; k0 += 32) {
#pragma unroll
    for (int r = 0; r < 2; ++r) {
      gload_lds16(A + (size_t)(m0 + r * 64 + srow) * KD + k0 + scol,
                  (char*)Al + r * 4096 + wave * 1024);
      gload_lds16(Bt + (size_t)(n0 + r * 64 + srow) * KD + k0 + scol,
                  (char*)Bl + r * 4096 + wave * 1024);
    }
    __syncthreads();
    bf16x8 af[4], bfr[4];
#pragma unroll
    for (int m = 0; m < 4; ++m)
      af[m] = *(const bf16x8*)&Al[(wr + m * 16 + (lane & 15)) * 32 + ka];
#pragma unroll
    for (int n = 0; n < 4; ++n)
      bfr[n] = *(const bf16x8*)&Bl[(wc + n * 16 + (lane & 15)) * 32 + ka];
#pragma unroll
    for (int m = 0; m < 4; ++m)
#pragma unroll
      for (int n = 0; n < 4; ++n)
        acc[m][n] = __builtin_amdgcn_mfma_f32_16x16x32_bf16(af[m], bfr[n], acc[m][n], 0, 0, 0);
    __syncthreads();
  }

#pragma unroll
  for (int m = 0; m < 4; ++m)
#pragma unroll
    for (int n = 0; n < 4; ++n)
#pragma unroll
      for (int j = 0; j < 4; ++j) {
        int row = m0 + wr + m * 16 + (lane >> 4) * 4 + j;
        int col = n0 + wc + n * 16 + (lane & 15);
        float v = acc[m][n][j] + bias[col];
        if (MODE == 1) {
          outF[(size_t)row * CDIM + col] = v;
        } else {
          int which = col >> 10;
          int h = (col >> 6) & 15;
          int d = col & 63;
          int b = row >> 11, t = row & (T_SEQ - 1);
          int bh = b * NHEAD + h;
          // Fold attention scale (1/sqrt(64) * log2e) into K.
          unsigned short bv = f2bf(which == 1 ? v * 0.18033688f : v);
          if (which == 0)      qb[((size_t)bh * T_SEQ + t) * HS + d] = bv;
          else if (which == 1) kb[((size_t)bh * T_SEQ + t) * HS + d] = bv;
          else                 vb[((size_t)bh * HS + d) * T_SEQ + t] = bv;
        }
      }
}

// Flash attention with KV-SPLIT. Block = 2 waves, SAME 32 q-rows, interleaved
// KV tiles (kt = wave, wave+2, ...). Each wave keeps private online-softmax
// state; wave 1 publishes (o,m,l) to LDS, one __syncthreads, wave 0 merges and
// stores. Halves the heavy wave's serial chain vs R3 AND doubles supply to
// 4 waves/SIMD. Per-wave structure identical to R3 (proven 85us): swapped
// QK^T (mfma(K,Q)) -> lane-local softmax (in-reg tree + 2 shfls), cvt_pk
// P -> padded LDS (PSTR 72, conflict-free), PV from V^T rows.
// K pre-scaled by 1/sqrt(hs)*log2e in GEMM1 epilogue (log2-domain scores).
// q,k: [bh][t][64] bf16; v: [bh][64][t] bf16 (transposed); y: [4096][1024] bf16.
#define PSTR 72
#define LOSTR 65
__global__ __launch_bounds__(128) void k_attn(const unsigned short* __restrict__ qb,
                                              const unsigned short* __restrict__ kb,
                                              const unsigned short* __restrict__ vb,
                                              unsigned short* __restrict__ yb) {
  __shared__ __align__(16) unsigned short Pl[2][32 * PSTR];
  __shared__ float Lo1[32 * LOSTR];
  __shared__ float Lm1[32];
  __shared__ float Ll1[32];
  // rid -> (xcd, bh, q-group). 8 XCDs x 4 bh x 64 groups. Heavy groups first.
  const int rid = blockIdx.x;
  const int xcd = rid & 7, i = rid >> 3;       // i in 0..255
  const int bh = xcd * 4 + (i & 3);
  const int g = 63 - (i >> 2);                 // 63 (heaviest) down to 0
  const int wave = threadIdx.x >> 6;
  const int lane = threadIdx.x & 63;
  const int l15 = lane & 15, lh = lane >> 4;
  const int q0 = g * 32;                       // block's 32 q-rows (both waves)
  const unsigned short* qh = qb + (size_t)bh * T_SEQ * HS;
  const unsigned short* kh = kb + (size_t)bh * T_SEQ * HS;
  const unsigned short* vh = vb + (size_t)bh * HS * T_SEQ;
  unsigned short* Pw = &Pl[wave][0];

  bf16x8 qf[2][2];
#pragma unroll
  for (int np = 0; np < 2; ++np)
#pragma unroll
    for (int kk = 0; kk < 2; ++kk)
      qf[np][kk] = *(const bf16x8*)&qh[(size_t)(q0 + np * 16 + l15) * HS + kk * 32 + lh * 8];

  f32x4 o[2][4];                 // PV layout: q = m*16 + lh*4 + j, d = n*16 + l15
  float Mx[2], Ls[2];            // softmax layout: q = np*16 + l15 (replicated over lh)
#pragma unroll
  for (int m = 0; m < 2; ++m) {
#pragma unroll
    for (int n = 0; n < 4; ++n) o[m][n] = f32x4{0.f, 0.f, 0.f, 0.f};
    Mx[m] = -INFINITY; Ls[m] = 0.f;
  }

  const int nkt = (q0 >> 6) + 1;

  bf16x8 kf[4][2], vf[4][2];
  // prologue: K fragments of this wave's first tile (kvb = wave*64, always in-bounds)
#pragma unroll
  for (int n = 0; n < 4; ++n)
#pragma unroll
    for (int kk = 0; kk < 2; ++kk)
      kf[n][kk] = *(const bf16x8*)&kh[(size_t)(wave * 64 + n * 16 + l15) * HS + kk * 32 + lh * 8];

  for (int kt = wave; kt < nkt; kt += 2) {
    const int kvb = kt * 64;
    // V fragments for THIS tile (used only after softmax -> latency hidden)
#pragma unroll
    for (int n = 0; n < 4; ++n)
#pragma unroll
      for (int kk = 0; kk < 2; ++kk)
        vf[n][kk] = *(const bf16x8*)&vh[(size_t)(n * 16 + l15) * T_SEQ + kvb + kk * 32 + lh * 8];

    // Swapped QK^T: s2[np][mp] = S^T block, q = np*16+l15, k = kvb+mp*16+lh*4+j
    f32x4 s2[2][4];
#pragma unroll
    for (int np = 0; np < 2; ++np)
#pragma unroll
      for (int mp = 0; mp < 4; ++mp) {
        f32x4 z = f32x4{0.f, 0.f, 0.f, 0.f};
        z = __builtin_amdgcn_mfma_f32_16x16x32_bf16(kf[mp][0], qf[np][0], z, 0, 0, 0);
        z = __builtin_amdgcn_mfma_f32_16x16x32_bf16(kf[mp][1], qf[np][1], z, 0, 0, 0);
        s2[np][mp] = z;
      }

    // K fragments for THIS WAVE'S NEXT tile (kt+2): old kf dead after MFMAs.
    if (kt + 2 < nkt) {
      const int kvb2 = kvb + 128;
#pragma unroll
      for (int n = 0; n < 4; ++n)
#pragma unroll
        for (int kk = 0; kk < 2; ++kk)
          kf[n][kk] = *(const bf16x8*)&kh[(size_t)(kvb2 + n * 16 + l15) * HS + kk * 32 + lh * 8];
    }

    const bool diag = (kvb + 63 > q0);
    float alpha_sm[2];
#pragma unroll
    for (int np = 0; np < 2; ++np) {
      const int qg = q0 + np * 16 + l15;
      if (diag) {
#pragma unroll
        for (int mp = 0; mp < 4; ++mp)
#pragma unroll
          for (int j = 0; j < 4; ++j)
            if (kvb + mp * 16 + lh * 4 + j > qg) s2[np][mp][j] = -3.0e38f;
      }
      // in-register row max (full ILP) + 2-shfl cross-quadrant reduce
      f32x4 t01, t23, t;
#pragma unroll
      for (int e = 0; e < 4; ++e) {
        t01[e] = fmaxf(s2[np][0][e], s2[np][1][e]);
        t23[e] = fmaxf(s2[np][2][e], s2[np][3][e]);
        t[e] = fmaxf(t01[e], t23[e]);
      }
      float mx = fmaxf(fmaxf(t[0], t[1]), fmaxf(t[2], t[3]));
      mx = fmaxf(mx, __shfl_xor(mx, 16));
      mx = fmaxf(mx, __shfl_xor(mx, 32));
      const float newM = fmaxf(Mx[np], mx);
      alpha_sm[np] = __builtin_exp2f(Mx[np] - newM);
      Mx[np] = newM;
      float rs = 0.f;
      uint2 w[4];
#pragma unroll
      for (int mp = 0; mp < 4; ++mp) {
        float p0 = __builtin_exp2f(s2[np][mp][0] - newM);
        float p1 = __builtin_exp2f(s2[np][mp][1] - newM);
        float p2 = __builtin_exp2f(s2[np][mp][2] - newM);
        float p3 = __builtin_exp2f(s2[np][mp][3] - newM);
        rs += (p0 + p1) + (p2 + p3);
        unsigned lo, hi;
        asm("v_cvt_pk_bf16_f32 %0, %1, %2" : "=v"(lo) : "v"(p0), "v"(p1));
        asm("v_cvt_pk_bf16_f32 %0, %1, %2" : "=v"(hi) : "v"(p2), "v"(p3));
        w[mp].x = lo; w[mp].y = hi;
      }
      rs += __shfl_xor(rs, 16);
      rs += __shfl_xor(rs, 32);
      Ls[np] = Ls[np] * alpha_sm[np] + rs;
#pragma unroll
      for (int mp = 0; mp < 4; ++mp)
        *(uint2*)&Pw[(np * 16 + l15) * PSTR + mp * 16 + lh * 4] = w[mp];
    }

    // broadcast alpha to PV layout (alpha replicated across lh -> segment pull ok)
#pragma unroll
    for (int m = 0; m < 2; ++m)
#pragma unroll
      for (int j = 0; j < 4; ++j) {
        const float a = __shfl(alpha_sm[m], lh * 4 + j, 16);
#pragma unroll
        for (int n = 0; n < 4; ++n) o[m][n][j] *= a;
      }

    __builtin_amdgcn_wave_barrier();  // keep ds_writes above the reads below

    bf16x8 pf[2][2];
#pragma unroll
    for (int m = 0; m < 2; ++m)
#pragma unroll
      for (int kk = 0; kk < 2; ++kk)
        pf[m][kk] = *(const bf16x8*)&Pw[(m * 16 + l15) * PSTR + kk * 32 + lh * 8];

#pragma unroll
    for (int m = 0; m < 2; ++m)
#pragma unroll
      for (int n = 0; n < 4; ++n) {
        o[m][n] = __builtin_amdgcn_mfma_f32_16x16x32_bf16(pf[m][0], vf[n][0], o[m][n], 0, 0, 0);
        o[m][n] = __builtin_amdgcn_mfma_f32_16x16x32_bf16(pf[m][1], vf[n][1], o[m][n], 0, 0, 0);
      }
  }

  // ---- KV-split merge: wave 1 publishes partials, wave 0 combines + stores.
  if (wave == 1) {
    if (lh == 0) {
#pragma unroll
      for (int np = 0; np < 2; ++np) {
        Lm1[np * 16 + l15] = Mx[np];
        Ll1[np * 16 + l15] = Ls[np];
      }
    }
#pragma unroll
    for (int m = 0; m < 2; ++m)
#pragma unroll
      for (int j = 0; j < 4; ++j)
#pragma unroll
        for (int n = 0; n < 4; ++n)
          Lo1[(m * 16 + lh * 4 + j) * LOSTR + n * 16 + l15] = o[m][n][j];
  }
  __syncthreads();
  if (wave == 0) {
    const int b = bh >> 4, h = bh & 15;
#pragma unroll
    for (int m = 0; m < 2; ++m)
#pragma unroll
      for (int j = 0; j < 4; ++j) {
        const int ql = m * 16 + lh * 4 + j;
        const float m0 = __shfl(Mx[m], lh * 4 + j, 16);
        const float l0 = __shfl(Ls[m], lh * 4 + j, 16);
        const float m1 = Lm1[ql], l1 = Ll1[ql];
        const float M = fmaxf(m0, m1);
        const float a0 = __builtin_exp2f(m0 - M);
        const float a1 = __builtin_exp2f(m1 - M);
        const float inv = 1.0f / (l0 * a0 + l1 * a1);
        const int tg = b * T_SEQ + q0 + ql;
#pragma unroll
        for (int n = 0; n < 4; ++n)
          yb[(size_t)tg * CDIM + h * 64 + n * 16 + l15] =
              f2bf((o[m][n][j] * a0 + Lo1[ql * LOSTR + n * 16 + l15] * a1) * inv);
      }
  }
}

extern "C" void kernel_launch(void* const* d_in, const int* in_sizes, int n_in,
                              void* d_out, int out_size, void* d_ws, size_t ws_size,
                              hipStream_t stream) {
  (void)in_sizes; (void)n_in; (void)out_size; (void)ws_size;
  const float* x      = (const float*)d_in[0];
  const float* W_attn = (const float*)d_in[1];
  const float* b_attn = (const float*)d_in[2];
  const float* W_proj = (const float*)d_in[3];
  const float* b_proj = (const float*)d_in[4];
  float* out = (float*)d_out;
  char* ws = (char*)d_ws;

  unsigned short* xb  = (unsigned short*)(ws);              //  8 MiB [4096][1024]
  unsigned short* Wta = (unsigned short*)(ws + 8388608);    //  6 MiB [3072][1024]
  unsigned short* Wtp = (unsigned short*)(ws + 14680064);   //  2 MiB [1024][1024]
  unsigned short* qbf = (unsigned short*)(ws + 16777216);   //  8 MiB [32][2048][64]
  unsigned short* kbf = (unsigned short*)(ws + 25165824);   //  8 MiB [32][2048][64]
  unsigned short* vbf = (unsigned short*)(ws + 33554432);   //  8 MiB [32][64][2048]
  unsigned short* ybf = (unsigned short*)(ws + 41943040);   //  8 MiB [4096][1024]

  k_cvt_x<<<4096, 256, 0, stream>>>(x, xb);
  k_transpose<<<dim3(96, 32), 256, 0, stream>>>(W_attn, Wta, 1024, 3072);
  k_transpose<<<dim3(32, 32), 256, 0, stream>>>(W_proj, Wtp, 1024, 1024);
  k_gemm<0, 1024><<<dim3(32, 24), 256, 0, stream>>>(xb, Wta, b_attn, nullptr, qbf, kbf, vbf);
  k_attn<<<2048, 128, 0, stream>>>(qbf, kbf, vbf, ybf);
  k_gemm<1, 1024><<<dim3(32, 8), 256, 0, stream>>>(ybf, Wtp, b_proj, out, nullptr, nullptr, nullptr);
}